// Round 2
// baseline (144.649 us; speedup 1.0000x reference)
//
#include <hip/hip_runtime.h>

#define NB 16
#define NT 50
#define NA 5
#define NH 152
#define NW 152
#define NC 7
#define CH 70            // NA*(7+NC)
#define HW (NH*NW)       // 23104
#define AHW (NA*HW)      // 115520
#define CELL_BLOCKS ((AHW + 255) / 256)   // 452
#define NBLK (CELL_BLOCKS * NB)           // 7232

// ws float-offsets (SoA descriptor arrays of length NB*NT = 800)
#define D_XLO 0
#define D_XHI 800
#define D_YLO 1600
#define D_YHI 2400
#define D_GW  3200
#define D_GL  4000
#define D_Q   4800
#define D_TW  5600
#define D_TL  6400
#define D_TIM 7200
#define D_TRE 8000
#define D_GX  8800
#define D_GY  9600
#define D_META 10400     // int array
#define P_CF  11264
#define P_BCE (11264 + NBLK)

// meta bits: gi[0:8) gj[8:16) best_n[16:19) anchmask[19:24) valid[24] validp[25] label[26:29)

__global__ void k_prep(const float* __restrict__ tgt,
                       const float* __restrict__ anchors,
                       float* __restrict__ ws) {
    int id = blockIdx.x * 256 + threadIdx.x;
    if (id >= NB * NT) return;
    int b = id / NT, t = id - b * NT;
    const float* tp = tgt + id * 7;
    float lab = tp[0], cx = tp[1], cy = tp[2], w = tp[3], l = tp[4];
    float tim = tp[5], tre = tp[6];
    float sum = lab + cx + cy + w + l + tim + tre;
    bool valid = (sum != 0.0f);
    bool validp = true;
    const float* tb = tgt + (size_t)b * NT * 7;
    for (int t2 = 0; t2 <= t; ++t2) validp = validp && (tb[t2 * 7 + 1] != 0.0f);

    float gx = cx * NW, gy = cy * NH, gw = w * NW, gl = l * NH;
    int gi = (int)gx; gi = min(max(gi, 0), NW - 1);
    int gj = (int)gy; gj = min(max(gj, 0), NH - 1);

    float agt = (gw + 1.f) * (gl + 1.f);
    float best = -1.f; int bn = 0; int am = 0;
    float aw_b = 1.f, ah_b = 1.f;
    for (int a = 0; a < NA; ++a) {
        float aw = anchors[2 * a], ah = anchors[2 * a + 1];
        float iw = fmaxf(fminf(gw, aw) + 1.f, 0.f);
        float ih = fmaxf(fminf(gl, ah) + 1.f, 0.f);
        float inter = iw * ih;
        float aan = (aw + 1.f) * (ah + 1.f);
        float iou = inter / (agt + aan - inter + 1e-16f);
        if (iou > best) { best = iou; bn = a; aw_b = aw; ah_b = ah; }
        if (iou > 0.6f) am |= (1 << a);
    }

    ws[D_XLO + id] = gx - 0.5f * gw;
    ws[D_XHI + id] = gx + 0.5f * gw;
    ws[D_YLO + id] = gy - 0.5f * gl;
    ws[D_YHI + id] = gy + 0.5f * gl;
    ws[D_GW + id]  = gw;
    ws[D_GL + id]  = gl;
    ws[D_Q + id]   = 0.375f * gw * gl;
    ws[D_TW + id]  = logf(gw / aw_b + 1e-16f);
    ws[D_TL + id]  = logf(gl / ah_b + 1e-16f);
    ws[D_TIM + id] = tim;
    ws[D_TRE + id] = tre;
    ws[D_GX + id]  = gx;
    ws[D_GY + id]  = gy;

    int meta = 0;
    if (valid || validp) {
        meta = gi | (gj << 8) | (bn << 16) | (am << 19)
             | (valid ? (1 << 24) : 0) | (validp ? (1 << 25) : 0)
             | ((((int)lab) & 7) << 26);
    }
    ((int*)ws)[D_META + id] = meta;
}

__global__ void __launch_bounds__(256) k_main(const float* __restrict__ x,
                                              const float* __restrict__ anchors,
                                              float* __restrict__ ws) {
    __shared__ float sxlo[NT], sxhi[NT], sylo[NT], syhi[NT];
    __shared__ float sgw[NT], sgl[NT], sq[NT];
    __shared__ int   smeta[NT];
    __shared__ float red0[256], red1[256];

    int b = blockIdx.y;
    int tid = threadIdx.x;
    if (tid < NT) {
        int id = b * NT + tid;
        sxlo[tid] = ws[D_XLO + id]; sxhi[tid] = ws[D_XHI + id];
        sylo[tid] = ws[D_YLO + id]; syhi[tid] = ws[D_YHI + id];
        sgw[tid]  = ws[D_GW + id];  sgl[tid]  = ws[D_GL + id];
        sq[tid]   = ws[D_Q + id];
        smeta[tid] = ((const int*)ws)[D_META + id];
    }
    __syncthreads();

    int p = blockIdx.x * 256 + tid;
    float s_cf = 0.f, s_bce = 0.f;
    if (p < AHW) {
        int a = p / HW;
        int rem = p - a * HW;
        int j = rem / NW;
        int i = rem - j * NW;
        const float* xp = x + (size_t)(b * CH + a * (7 + NC)) * HW + rem;
        float l0 = xp[0], l1 = xp[HW], l2 = xp[2 * HW], l3 = xp[3 * HW], l6 = xp[6 * HW];
        float aw = anchors[2 * a], ah = anchors[2 * a + 1];
        float px = 1.f / (1.f + __expf(-l0));
        float py = 1.f / (1.f + __expf(-l1));
        float bw = __expf(l2) * aw;
        float bh = __expf(l3) * ah;
        float bx = px + (float)i, by = py + (float)j;
        float hw2 = 0.5f * bw, hh2 = 0.5f * bh;
        float bxlo = bx - hw2, bxhi = bx + hw2;
        float bylo = by - hh2, byhi = by + hh2;
        float qb = 0.375f * bw * bh;
        int ji = i | (j << 8);

        bool sawHigh = false, sawZero = false, sawOne = false;
        for (int t = 0; t < NT; ++t) {
            int mt = smeta[t];
            if (mt == 0) continue;
            if (mt & (1 << 25)) {   // valid_prefix: IoU contributes to cur_ious
                float mx = fminf(bxlo, sxlo[t]);
                float Mx = fmaxf(bxhi, sxhi[t]);
                float my = fminf(bylo, sylo[t]);
                float My = fmaxf(byhi, syhi[t]);
                float cw = bw + sgw[t] - (Mx - mx);
                float chh = bh + sgl[t] - (My - my);
                // iou > 0.6  <=>  carea > 0.375*(area_b + area_g)
                if (cw > 0.f && chh > 0.f && cw * chh > qb + sq[t]) sawHigh = true;
            }
            if ((mt & (1 << 24)) && ((mt & 0xFFFF) == ji)) {  // valid, same cell
                if ((mt >> (19 + a)) & 1) sawZero = true;     // anch_iou[a] > thres
                if (((mt >> 16) & 7) == a) sawOne = true;     // best_n == a
            }
        }
        // np-wrap semantics: the last grid cell (b=NB-1, a=NA-1, j=NH-1, i=NW-1)
        // receives all fi==-1 scatters -> it is a mask cell (m=1) -> cf=0 there.
        bool isCstar = (b == NB - 1) && (p == AHW - 1);
        // conf = sawOne?1 : sawZero?0 : (sawHigh?0:1);  m = sawOne (or c*)
        // cf = conf*(1-m) = !(sawOne||sawZero||sawHigh||c*)
        if (!(sawHigh || sawZero || sawOne || isCstar)) {
            s_cf = 1.f;
            // tconf=0 here: bce = -log(1-sigmoid(l6)) = softplus(l6)
            s_bce = (l6 > 20.f) ? l6 : __logf(1.f + __expf(l6));
        }
    }
    red0[tid] = s_cf; red1[tid] = s_bce;
    __syncthreads();
    for (int s = 128; s > 0; s >>= 1) {
        if (tid < s) { red0[tid] += red0[tid + s]; red1[tid] += red1[tid + s]; }
        __syncthreads();
    }
    if (tid == 0) {
        int blk = b * CELL_BLOCKS + blockIdx.x;
        ws[P_CF + blk] = red0[0];
        ws[P_BCE + blk] = red1[0];
    }
}

__global__ void __launch_bounds__(256) k_final(const float* __restrict__ x,
                                               const float* __restrict__ ws,
                                               float* __restrict__ out) {
    int tid = threadIdx.x;
    const int* meta = (const int*)ws + D_META;
    float v[8];  // Sx,Sy,Sw,Sh,Seu,Sb1,Sce,cnt
    for (int k = 0; k < 8; ++k) v[k] = 0.f;

    for (int id = tid; id < NB * NT; id += 256) {
        int mt = meta[id];
        if (!(mt & (1 << 24))) continue;   // not valid
        int b = id / NT, t = id - b * NT;
        int key = mt & 0x7FFFF;            // gi|gj|bn
        bool winner = true;
        for (int t2 = t + 1; t2 < NT; ++t2) {
            int m2 = meta[b * NT + t2];
            if ((m2 & (1 << 24)) && ((m2 & 0x7FFFF) == key)) { winner = false; break; }
        }
        if (!winner) continue;             // last-t-wins (np scatter order)

        int gi = mt & 255, gj = (mt >> 8) & 255;
        int bn = (mt >> 16) & 7, lab = (mt >> 26) & 7;
        const float* xp = x + (size_t)(b * CH + bn * (7 + NC)) * HW + gj * NW + gi;
        float l[14];
        for (int c = 0; c < 14; ++c) l[c] = xp[c * HW];

        float tx = ws[D_GX + id] - (float)gi;
        float ty = ws[D_GY + id] - (float)gj;
        float px = 1.f / (1.f + __expf(-l[0]));
        float py = 1.f / (1.f + __expf(-l[1]));
        v[0] += (px - tx) * (px - tx);
        v[1] += (py - ty) * (py - ty);
        float dw = l[2] - ws[D_TW + id]; v[2] += dw * dw;
        float dh = l[3] - ws[D_TL + id]; v[3] += dh * dh;
        float di = l[4] - ws[D_TIM + id];
        float dr = l[5] - ws[D_TRE + id];
        v[4] += di * di + dr * dr;
        // tconf=1 cell: bce = -log(sigmoid(l6)) = softplus(-l6)
        float nl = -l[6];
        v[5] += (nl > 20.f) ? nl : __logf(1.f + __expf(nl));
        // cls: ce = logsumexp(softmax(logits)) - softmax(logits)[lab]
        float mx = l[7];
        for (int c = 8; c < 14; ++c) mx = fmaxf(mx, l[c]);
        float e[7], se = 0.f;
        for (int c = 0; c < 7; ++c) { e[c] = __expf(l[7 + c] - mx); se += e[c]; }
        float s[7], se2 = 0.f;
        for (int c = 0; c < 7; ++c) { s[c] = e[c] / se; se2 += __expf(s[c]); }
        v[6] += __logf(se2) - s[lab];
        v[7] += 1.f;
    }

    // np negative-index wrap: cell c* = (NB-1, NA-1, NH-1, NW-1) is a mask cell
    // with winner values from the last invalid (all-zero) target row:
    // tx=ty=tim=tre=0, tw=tl=log(1e-16), label=0, tconf=1.
    if (tid == 0) {
        const float* xp = x + (size_t)((NB - 1) * CH + (NA - 1) * (7 + NC)) * HW + (HW - 1);
        float l[14];
        for (int c = 0; c < 14; ++c) l[c] = xp[c * HW];
        const float L16 = logf(1e-16f);   // -36.8414
        float px = 1.f / (1.f + __expf(-l[0]));
        float py = 1.f / (1.f + __expf(-l[1]));
        v[0] += px * px;
        v[1] += py * py;
        float dw = l[2] - L16; v[2] += dw * dw;
        float dh = l[3] - L16; v[3] += dh * dh;
        v[4] += l[4] * l[4] + l[5] * l[5];
        float nl = -l[6];
        v[5] += (nl > 20.f) ? nl : __logf(1.f + __expf(nl));
        float mx = l[7];
        for (int c = 8; c < 14; ++c) mx = fmaxf(mx, l[c]);
        float e[7], se = 0.f;
        for (int c = 0; c < 7; ++c) { e[c] = __expf(l[7 + c] - mx); se += e[c]; }
        float s[7], se2 = 0.f;
        for (int c = 0; c < 7; ++c) { s[c] = e[c] / se; se2 += __expf(s[c]); }
        v[6] += __logf(se2) - s[0];
        v[7] += 1.f;
    }

    __shared__ float r[8][256];
    for (int k = 0; k < 8; ++k) r[k][tid] = v[k];
    __syncthreads();
    for (int st = 128; st > 0; st >>= 1) {
        if (tid < st)
            for (int k = 0; k < 8; ++k) r[k][tid] += r[k][tid + st];
        __syncthreads();
    }

    // reduce K2 partials in double (deterministic: fixed stride + tree)
    __shared__ double dcf[256], dbce[256];
    double acf = 0.0, abce = 0.0;
    for (int idx = tid; idx < NBLK; idx += 256) {
        acf += (double)ws[P_CF + idx];
        abce += (double)ws[P_BCE + idx];
    }
    dcf[tid] = acf; dbce[tid] = abce;
    __syncthreads();
    for (int st = 128; st > 0; st >>= 1) {
        if (tid < st) { dcf[tid] += dcf[tid + st]; dbce[tid] += dbce[tid + st]; }
        __syncthreads();
    }

    if (tid == 0) {
        double nM = fmax((double)r[7][0], 1.0);
        double scf = fmax(dcf[0], 1.0);
        double loss =
            ((double)r[0][0] + r[1][0] + r[2][0] + r[3][0] + r[4][0] + r[5][0]) / nM
            + dbce[0] / scf
            + (1.0 / NB) * (double)r[6][0] / nM;
        out[0] = (float)loss;
    }
}

extern "C" void kernel_launch(void* const* d_in, const int* in_sizes, int n_in,
                              void* d_out, int out_size, void* d_ws, size_t ws_size,
                              hipStream_t stream) {
    const float* x   = (const float*)d_in[0];
    const float* tgt = (const float*)d_in[1];
    const float* anc = (const float*)d_in[2];
    float* ws  = (float*)d_ws;
    float* out = (float*)d_out;

    hipLaunchKernelGGL(k_prep, dim3((NB * NT + 255) / 256), dim3(256), 0, stream,
                       tgt, anc, ws);
    hipLaunchKernelGGL(k_main, dim3(CELL_BLOCKS, NB), dim3(256), 0, stream,
                       x, anc, ws);
    hipLaunchKernelGGL(k_final, dim3(1), dim3(256), 0, stream, x, ws, out);
}

// Round 3
// 73.905 us; speedup vs baseline: 1.9572x; 1.9572x over previous
//
#include <hip/hip_runtime.h>

#define NB 16
#define NT 50
#define NA 5
#define NH 152
#define NW 152
#define NC 7
#define CH 70            // NA*(7+NC)
#define HW (NH*NW)       // 23104
#define AHW (NA*HW)      // 115520
#define NCELL (NB*AHW)   // 1,848,320
#define NWORDS (NCELL/32) // 57,760

// old gather-path geometry (fallback)
#define CELL_BLOCKS ((AHW + 255) / 256)   // 452
#define NBLK (CELL_BLOCKS * NB)           // 7232
// new sum-path geometry
#define SUM_BLOCKS (NCELL / 1024)         // 1805 (exact)

// ws float-offsets (SoA descriptor arrays of length NB*NT = 800)
#define D_XLO 0
#define D_XHI 800
#define D_YLO 1600
#define D_YHI 2400
#define D_GW  3200
#define D_GL  4000
#define D_Q   4800
#define D_TW  5600
#define D_TL  6400
#define D_TIM 7200
#define D_TRE 8000
#define D_GX  8800
#define D_GY  9600
#define D_META 10400     // int array
#define P_CF  11264      // partials; P_BCE = P_CF + npart
#define M_WORD 16384     // u32 index of mask bits (new path)
#define WS_NEED ((M_WORD + NWORDS) * 4)

// meta bits: gi[0:8) gj[8:16) best_n[16:19) anchmask[19:24) valid[24] validp[25] label[26:29)

__device__ __forceinline__ void prep_one(int id, const float* __restrict__ tgt,
                                         const float* __restrict__ anchors,
                                         float* __restrict__ ws) {
    int b = id / NT, t = id - b * NT;
    const float* tp = tgt + id * 7;
    float lab = tp[0], cx = tp[1], cy = tp[2], w = tp[3], l = tp[4];
    float tim = tp[5], tre = tp[6];
    float sum = lab + cx + cy + w + l + tim + tre;
    bool valid = (sum != 0.0f);
    bool validp = true;
    const float* tb = tgt + (size_t)b * NT * 7;
    for (int t2 = 0; t2 <= t; ++t2) validp = validp && (tb[t2 * 7 + 1] != 0.0f);

    float gx = cx * NW, gy = cy * NH, gw = w * NW, gl = l * NH;
    int gi = (int)gx; gi = min(max(gi, 0), NW - 1);
    int gj = (int)gy; gj = min(max(gj, 0), NH - 1);

    float agt = (gw + 1.f) * (gl + 1.f);
    float best = -1.f; int bn = 0; int am = 0;
    float aw_b = 1.f, ah_b = 1.f;
    for (int a = 0; a < NA; ++a) {
        float aw = anchors[2 * a], ah = anchors[2 * a + 1];
        float iw = fmaxf(fminf(gw, aw) + 1.f, 0.f);
        float ih = fmaxf(fminf(gl, ah) + 1.f, 0.f);
        float inter = iw * ih;
        float aan = (aw + 1.f) * (ah + 1.f);
        float iou = inter / (agt + aan - inter + 1e-16f);
        if (iou > best) { best = iou; bn = a; aw_b = aw; ah_b = ah; }
        if (iou > 0.6f) am |= (1 << a);
    }

    ws[D_XLO + id] = gx - 0.5f * gw;
    ws[D_XHI + id] = gx + 0.5f * gw;
    ws[D_YLO + id] = gy - 0.5f * gl;
    ws[D_YHI + id] = gy + 0.5f * gl;
    ws[D_GW + id]  = gw;
    ws[D_GL + id]  = gl;
    ws[D_Q + id]   = 0.375f * gw * gl;
    ws[D_TW + id]  = logf(gw / aw_b + 1e-16f);
    ws[D_TL + id]  = logf(gl / ah_b + 1e-16f);
    ws[D_TIM + id] = tim;
    ws[D_TRE + id] = tre;
    ws[D_GX + id]  = gx;
    ws[D_GY + id]  = gy;

    int meta = 0;
    if (valid || validp) {
        meta = gi | (gj << 8) | (bn << 16) | (am << 19)
             | (valid ? (1 << 24) : 0) | (validp ? (1 << 25) : 0)
             | ((((int)lab) & 7) << 26);
    }
    ((int*)ws)[D_META + id] = meta;
}

// ---------- new path: K0 prep + zero mask ----------
__global__ void __launch_bounds__(256) k_prep_zero(const float* __restrict__ tgt,
                                                   const float* __restrict__ anchors,
                                                   float* __restrict__ ws) {
    int gtid = blockIdx.x * 256 + threadIdx.x;
    if (gtid < NWORDS) ((unsigned int*)ws)[M_WORD + gtid] = 0u;
    if (gtid < NB * NT) prep_one(gtid, tgt, anchors, ws);
}

// ---------- new path: K1 scatter IoU + overrides ----------
__global__ void __launch_bounds__(256) k_iou(const float* __restrict__ x,
                                             const float* __restrict__ anchors,
                                             float* __restrict__ ws) {
    int t = blockIdx.x, b = blockIdx.y;
    int id = b * NT + t;
    int mt = ((const int*)ws)[D_META + id];
    if (mt == 0) return;
    unsigned int* mask = (unsigned int*)ws + M_WORD;

    // overrides: cells excluded from cf (conf forced 0 or m=1)
    if ((mt & (1 << 24)) && threadIdx.x == 0) {
        int gi = mt & 255, gj = (mt >> 8) & 255;
        int bn = (mt >> 16) & 7, am = (mt >> 19) & 31;
        for (int a = 0; a < NA; ++a) {
            if (((am >> a) & 1) || a == bn) {
                int c = ((b * NA + a) * NH + gj) * NW + gi;
                atomicOr(&mask[c >> 5], 1u << (c & 31));
            }
        }
    }
    if (!(mt & (1 << 25))) return;   // IoU only for valid_prefix targets

    float gx  = ws[D_GX + id],  gy  = ws[D_GY + id];
    float tgw = ws[D_GW + id],  tgl = ws[D_GL + id];
    float txlo = ws[D_XLO + id], txhi = ws[D_XHI + id];
    float tylo = ws[D_YLO + id], tyhi = ws[D_YHI + id];
    float tq = ws[D_Q + id];
    if (tgw <= 0.f || tgl <= 0.f) return;

    // proven reach: pass => |bx-gx| < tgw/3 and |by-gy| < tgl/3 (+1 cell margin)
    float gw3 = tgw * (1.f / 3.f), gl3 = tgl * (1.f / 3.f);
    int i_lo = max(0, (int)floorf(gx - gw3) - 1);
    int i_hi = min(NW - 1, (int)floorf(gx + gw3) + 1);
    int j_lo = max(0, (int)floorf(gy - gl3) - 1);
    int j_hi = min(NH - 1, (int)floorf(gy + gl3) + 1);
    int W = i_hi - i_lo + 1, Hh = j_hi - j_lo + 1;
    int total = W * Hh * NA;

    for (int idx = threadIdx.x; idx < total; idx += 256) {
        int dx = idx % W;
        int q = idx / W;
        int j = j_lo + q % Hh;
        int a = q / Hh;
        int i = i_lo + dx;
        const float* xp = x + (size_t)(b * CH + a * (7 + NC)) * HW + j * NW + i;
        float l0 = xp[0], l1 = xp[HW], l2 = xp[2 * HW], l3 = xp[3 * HW];
        float aw = anchors[2 * a], ah = anchors[2 * a + 1];
        float bx = (float)i + 1.f / (1.f + __expf(-l0));
        float by = (float)j + 1.f / (1.f + __expf(-l1));
        float bw = __expf(l2) * aw;
        float bh = __expf(l3) * ah;
        float mx = fminf(bx - 0.5f * bw, txlo);
        float Mx = fmaxf(bx + 0.5f * bw, txhi);
        float my = fminf(by - 0.5f * bh, tylo);
        float My = fmaxf(by + 0.5f * bh, tyhi);
        float cw = bw + tgw - (Mx - mx);
        float ch = bh + tgl - (My - my);
        if (cw > 0.f && ch > 0.f && cw * ch > 0.375f * bw * bh + tq) {
            int c = ((b * NA + a) * NH + j) * NW + i;
            atomicOr(&mask[c >> 5], 1u << (c & 31));
        }
    }
}

// ---------- new path: K2 masked bce sum ----------
__global__ void __launch_bounds__(256) k_sum(const float* __restrict__ x,
                                             float* __restrict__ ws) {
    __shared__ float red0[256], red1[256];
    int tid = threadIdx.x;
    int c4 = (blockIdx.x * 256 + tid) * 4;   // 4 cells, same (b,a) channel
    int b = c4 / AHW;
    int within = c4 - b * AHW;
    int a = within / HW;
    int rem = within - a * HW;
    const float* l6p = x + (size_t)(b * CH + a * (7 + NC) + 6) * HW + rem;
    float4 l6 = *(const float4*)l6p;
    unsigned int word = ((const unsigned int*)ws)[M_WORD + (c4 >> 5)];
    unsigned int sh = (unsigned)(c4 & 31);

    float s_cf = 0.f, s_bce = 0.f;
    float l6v[4] = {l6.x, l6.y, l6.z, l6.w};
    #pragma unroll
    for (int k = 0; k < 4; ++k) {
        bool excl = (word >> (sh + k)) & 1u;
        if (c4 + k == NCELL - 1) excl = true;   // np wrap cell c*
        if (!excl) {
            s_cf += 1.f;
            float v = l6v[k];
            s_bce += (v > 20.f) ? v : __logf(1.f + __expf(v));
        }
    }
    red0[tid] = s_cf; red1[tid] = s_bce;
    __syncthreads();
    for (int s = 128; s > 0; s >>= 1) {
        if (tid < s) { red0[tid] += red0[tid + s]; red1[tid] += red1[tid + s]; }
        __syncthreads();
    }
    if (tid == 0) {
        ws[P_CF + blockIdx.x] = red0[0];
        ws[P_CF + SUM_BLOCKS + blockIdx.x] = red1[0];
    }
}

// ---------- fallback path: old kernels ----------
__global__ void k_prep(const float* __restrict__ tgt,
                       const float* __restrict__ anchors,
                       float* __restrict__ ws) {
    int id = blockIdx.x * 256 + threadIdx.x;
    if (id >= NB * NT) return;
    prep_one(id, tgt, anchors, ws);
}

__global__ void __launch_bounds__(256) k_main(const float* __restrict__ x,
                                              const float* __restrict__ anchors,
                                              float* __restrict__ ws) {
    __shared__ float sxlo[NT], sxhi[NT], sylo[NT], syhi[NT];
    __shared__ float sgw[NT], sgl[NT], sq[NT];
    __shared__ int   smeta[NT];
    __shared__ float red0[256], red1[256];

    int b = blockIdx.y;
    int tid = threadIdx.x;
    if (tid < NT) {
        int id = b * NT + tid;
        sxlo[tid] = ws[D_XLO + id]; sxhi[tid] = ws[D_XHI + id];
        sylo[tid] = ws[D_YLO + id]; syhi[tid] = ws[D_YHI + id];
        sgw[tid]  = ws[D_GW + id];  sgl[tid]  = ws[D_GL + id];
        sq[tid]   = ws[D_Q + id];
        smeta[tid] = ((const int*)ws)[D_META + id];
    }
    __syncthreads();

    int p = blockIdx.x * 256 + tid;
    float s_cf = 0.f, s_bce = 0.f;
    if (p < AHW) {
        int a = p / HW;
        int rem = p - a * HW;
        int j = rem / NW;
        int i = rem - j * NW;
        const float* xp = x + (size_t)(b * CH + a * (7 + NC)) * HW + rem;
        float l0 = xp[0], l1 = xp[HW], l2 = xp[2 * HW], l3 = xp[3 * HW], l6 = xp[6 * HW];
        float aw = anchors[2 * a], ah = anchors[2 * a + 1];
        float px = 1.f / (1.f + __expf(-l0));
        float py = 1.f / (1.f + __expf(-l1));
        float bw = __expf(l2) * aw;
        float bh = __expf(l3) * ah;
        float bx = px + (float)i, by = py + (float)j;
        float bxlo = bx - 0.5f * bw, bxhi = bx + 0.5f * bw;
        float bylo = by - 0.5f * bh, byhi = by + 0.5f * bh;
        float qb = 0.375f * bw * bh;
        int ji = i | (j << 8);

        bool sawHigh = false, sawZero = false, sawOne = false;
        for (int t = 0; t < NT; ++t) {
            int mt = smeta[t];
            if (mt == 0) continue;
            if (mt & (1 << 25)) {
                float mx = fminf(bxlo, sxlo[t]);
                float Mx = fmaxf(bxhi, sxhi[t]);
                float my = fminf(bylo, sylo[t]);
                float My = fmaxf(byhi, syhi[t]);
                float cw = bw + sgw[t] - (Mx - mx);
                float chh = bh + sgl[t] - (My - my);
                if (cw > 0.f && chh > 0.f && cw * chh > qb + sq[t]) sawHigh = true;
            }
            if ((mt & (1 << 24)) && ((mt & 0xFFFF) == ji)) {
                if ((mt >> (19 + a)) & 1) sawZero = true;
                if (((mt >> 16) & 7) == a) sawOne = true;
            }
        }
        bool isCstar = (b == NB - 1) && (p == AHW - 1);
        if (!(sawHigh || sawZero || sawOne || isCstar)) {
            s_cf = 1.f;
            s_bce = (l6 > 20.f) ? l6 : __logf(1.f + __expf(l6));
        }
    }
    red0[tid] = s_cf; red1[tid] = s_bce;
    __syncthreads();
    for (int s = 128; s > 0; s >>= 1) {
        if (tid < s) { red0[tid] += red0[tid + s]; red1[tid] += red1[tid + s]; }
        __syncthreads();
    }
    if (tid == 0) {
        int blk = b * CELL_BLOCKS + blockIdx.x;
        ws[P_CF + blk] = red0[0];
        ws[P_CF + NBLK + blk] = red1[0];
    }
}

// ---------- shared final kernel (npart parameterized) ----------
__global__ void __launch_bounds__(256) k_final(const float* __restrict__ x,
                                               const float* __restrict__ ws,
                                               float* __restrict__ out,
                                               int npart) {
    int tid = threadIdx.x;
    const int* meta = (const int*)ws + D_META;
    float v[8];  // Sx,Sy,Sw,Sh,Seu,Sb1,Sce,cnt
    for (int k = 0; k < 8; ++k) v[k] = 0.f;

    for (int id = tid; id < NB * NT; id += 256) {
        int mt = meta[id];
        if (!(mt & (1 << 24))) continue;
        int b = id / NT, t = id - b * NT;
        int key = mt & 0x7FFFF;
        bool winner = true;
        for (int t2 = t + 1; t2 < NT; ++t2) {
            int m2 = meta[b * NT + t2];
            if ((m2 & (1 << 24)) && ((m2 & 0x7FFFF) == key)) { winner = false; break; }
        }
        if (!winner) continue;             // last-t-wins (np scatter order)

        int gi = mt & 255, gj = (mt >> 8) & 255;
        int bn = (mt >> 16) & 7, lab = (mt >> 26) & 7;
        const float* xp = x + (size_t)(b * CH + bn * (7 + NC)) * HW + gj * NW + gi;
        float l[14];
        for (int c = 0; c < 14; ++c) l[c] = xp[c * HW];

        float tx = ws[D_GX + id] - (float)gi;
        float ty = ws[D_GY + id] - (float)gj;
        float px = 1.f / (1.f + __expf(-l[0]));
        float py = 1.f / (1.f + __expf(-l[1]));
        v[0] += (px - tx) * (px - tx);
        v[1] += (py - ty) * (py - ty);
        float dw = l[2] - ws[D_TW + id]; v[2] += dw * dw;
        float dh = l[3] - ws[D_TL + id]; v[3] += dh * dh;
        float di = l[4] - ws[D_TIM + id];
        float dr = l[5] - ws[D_TRE + id];
        v[4] += di * di + dr * dr;
        float nl = -l[6];
        v[5] += (nl > 20.f) ? nl : __logf(1.f + __expf(nl));
        float mx = l[7];
        for (int c = 8; c < 14; ++c) mx = fmaxf(mx, l[c]);
        float e[7], se = 0.f;
        for (int c = 0; c < 7; ++c) { e[c] = __expf(l[7 + c] - mx); se += e[c]; }
        float s[7], se2 = 0.f;
        for (int c = 0; c < 7; ++c) { s[c] = e[c] / se; se2 += __expf(s[c]); }
        v[6] += __logf(se2) - s[lab];
        v[7] += 1.f;
    }

    // np wrap cell c*: winner values from last invalid (all-zero) row
    if (tid == 0) {
        const float* xp = x + (size_t)((NB - 1) * CH + (NA - 1) * (7 + NC)) * HW + (HW - 1);
        float l[14];
        for (int c = 0; c < 14; ++c) l[c] = xp[c * HW];
        const float L16 = logf(1e-16f);
        float px = 1.f / (1.f + __expf(-l[0]));
        float py = 1.f / (1.f + __expf(-l[1]));
        v[0] += px * px;
        v[1] += py * py;
        float dw = l[2] - L16; v[2] += dw * dw;
        float dh = l[3] - L16; v[3] += dh * dh;
        v[4] += l[4] * l[4] + l[5] * l[5];
        float nl = -l[6];
        v[5] += (nl > 20.f) ? nl : __logf(1.f + __expf(nl));
        float mx = l[7];
        for (int c = 8; c < 14; ++c) mx = fmaxf(mx, l[c]);
        float e[7], se = 0.f;
        for (int c = 0; c < 7; ++c) { e[c] = __expf(l[7 + c] - mx); se += e[c]; }
        float s[7], se2 = 0.f;
        for (int c = 0; c < 7; ++c) { s[c] = e[c] / se; se2 += __expf(s[c]); }
        v[6] += __logf(se2) - s[0];
        v[7] += 1.f;
    }

    __shared__ float r[8][256];
    for (int k = 0; k < 8; ++k) r[k][tid] = v[k];
    __syncthreads();
    for (int st = 128; st > 0; st >>= 1) {
        if (tid < st)
            for (int k = 0; k < 8; ++k) r[k][tid] += r[k][tid + st];
        __syncthreads();
    }

    __shared__ double dcf[256], dbce[256];
    double acf = 0.0, abce = 0.0;
    for (int idx = tid; idx < npart; idx += 256) {
        acf += (double)ws[P_CF + idx];
        abce += (double)ws[P_CF + npart + idx];
    }
    dcf[tid] = acf; dbce[tid] = abce;
    __syncthreads();
    for (int st = 128; st > 0; st >>= 1) {
        if (tid < st) { dcf[tid] += dcf[tid + st]; dbce[tid] += dbce[tid + st]; }
        __syncthreads();
    }

    if (tid == 0) {
        double nM = fmax((double)r[7][0], 1.0);
        double scf = fmax(dcf[0], 1.0);
        double loss =
            ((double)r[0][0] + r[1][0] + r[2][0] + r[3][0] + r[4][0] + r[5][0]) / nM
            + dbce[0] / scf
            + (1.0 / NB) * (double)r[6][0] / nM;
        out[0] = (float)loss;
    }
}

extern "C" void kernel_launch(void* const* d_in, const int* in_sizes, int n_in,
                              void* d_out, int out_size, void* d_ws, size_t ws_size,
                              hipStream_t stream) {
    const float* x   = (const float*)d_in[0];
    const float* tgt = (const float*)d_in[1];
    const float* anc = (const float*)d_in[2];
    float* ws  = (float*)d_ws;
    float* out = (float*)d_out;

    if (ws_size >= (size_t)WS_NEED) {
        hipLaunchKernelGGL(k_prep_zero, dim3((NWORDS + 255) / 256), dim3(256), 0, stream,
                           tgt, anc, ws);
        hipLaunchKernelGGL(k_iou, dim3(NT, NB), dim3(256), 0, stream, x, anc, ws);
        hipLaunchKernelGGL(k_sum, dim3(SUM_BLOCKS), dim3(256), 0, stream, x, ws);
        hipLaunchKernelGGL(k_final, dim3(1), dim3(256), 0, stream, x, ws, out, SUM_BLOCKS);
    } else {
        hipLaunchKernelGGL(k_prep, dim3((NB * NT + 255) / 256), dim3(256), 0, stream,
                           tgt, anc, ws);
        hipLaunchKernelGGL(k_main, dim3(CELL_BLOCKS, NB), dim3(256), 0, stream,
                           x, anc, ws);
        hipLaunchKernelGGL(k_final, dim3(1), dim3(256), 0, stream, x, ws, out, NBLK);
    }
}